// Round 14
// baseline (32.490 us; speedup 1.0000x reference)
//
#include <hip/hip_runtime.h>

#define NRAYS 8192
#define NSAMP 173
#define LASTI 172
#define NBLK  (NRAYS / 4)

__device__ __forceinline__ float RL(float x, int u) {
    return __int_as_float(__builtin_amdgcn_readlane(__float_as_int(x), u));
}

template <int CTRL, int RM, bool BC>
__device__ __forceinline__ float updpp(float old, float x) {
    return __int_as_float(__builtin_amdgcn_update_dpp(
        __float_as_int(old), __float_as_int(x), CTRL, RM, 0xf, BC));
}

// wave64 inclusive add-scan (DPP)
__device__ __forceinline__ float scan_add64(float x) {
    x += updpp<0x111, 0xf, true>(0.f, x);
    x += updpp<0x112, 0xf, true>(0.f, x);
    x += updpp<0x114, 0xf, true>(0.f, x);
    x += updpp<0x118, 0xf, true>(0.f, x);
    x += updpp<0x142, 0xa, true>(0.f, x);
    x += updpp<0x143, 0xc, true>(0.f, x);
    return x;
}

// wave64 inclusive mul-scan (DPP)
__device__ __forceinline__ float scan_mul64(float x) {
    x *= updpp<0x111, 0xf, false>(1.f, x);
    x *= updpp<0x112, 0xf, false>(1.f, x);
    x *= updpp<0x114, 0xf, false>(1.f, x);
    x *= updpp<0x118, 0xf, false>(1.f, x);
    x *= updpp<0x142, 0xa, false>(1.f, x);
    x *= updpp<0x143, 0xc, false>(1.f, x);
    return x;
}

__device__ __forceinline__ float wave_sum64(float v) {
    return RL(scan_add64(v), 63);
}

__device__ __forceinline__ float softplus_f(float x) {
    if (x > 15.f) return x;
    return __logf(1.f + __expf(x));
}
__device__ __forceinline__ float sigmoid_f(float x) {
    return 1.f / (1.f + __expf(-x));
}

__launch_bounds__(256, 4)
__global__ void render_kernel(
    const float* __restrict__ rays,
    const float* __restrict__ Wd1, const float* __restrict__ bd1,
    const float* __restrict__ Wd2, const float* __restrict__ bd2,
    const float* __restrict__ Wapp, const float* __restrict__ Wa1,
    const float* __restrict__ ba1, const float* __restrict__ Wa2,
    const float* __restrict__ ba2, const float* __restrict__ Wsf,
    const float* __restrict__ Wsm, const float* __restrict__ bsm,
    const float* __restrict__ Wi,
    const int* __restrict__ whitebg_p,
    float* __restrict__ out,
    float* __restrict__ wsdist)
{
    // per-RAY z-linear MLP coefficients (h_u(z) = z*g_u + k_u) + block tables
    __shared__ float4 gkwD[4][64];  // density:    (gd, kd, wd2, 0)   per ray x unit
    __shared__ float2 gkA[4][64];   // appearance: (ga, ka)           per ray x unit
    __shared__ float4 bQ[64];       // block: (Wa2[u][0..2], 0)
    __shared__ float4 apAs[64];     // fold temp: wac triple = Wapp @ Wa1[:27]
    __shared__ float  wscs[60];     // (Wsf @ Wsm)
    __shared__ float  bsmS[20];

    const int t = threadIdx.x;
    const int wid = t >> 6, lane = t & 63;
    const int r = blockIdx.x * 4 + wid;

    // ---- block fold phase ----
    if (t < 64) {
        bQ[t] = make_float4(Wa2[3 * t], Wa2[3 * t + 1], Wa2[3 * t + 2], 0.f);
    } else if (t >= 128 && t < 192) {
        int u = t - 128;
        float s0 = 0.f, s1 = 0.f, s2 = 0.f;
        for (int j = 0; j < 27; ++j) {
            float w = Wa1[j * 64 + u];
            s0 = fmaf(Wapp[j], w, s0);
            s1 = fmaf(Wapp[27 + j], w, s1);
            s2 = fmaf(Wapp[54 + j], w, s2);
        }
        apAs[u] = make_float4(s0, s1, s2, 0.f);
    } else if (t >= 192) {
        for (int job = t - 192; job < 80; job += 64) {
            if (job < 60) {
                int m = job / 20, s = job % 20;
                float a = 0.f;
                for (int k = 0; k < 32; ++k) a = fmaf(Wsf[m * 32 + k], Wsm[k * 20 + s], a);
                wscs[job] = a;
            } else {
                bsmS[job - 60] = bsm[job - 60];
            }
        }
    }

    // ray (wave-uniform)
    const float o0 = rays[r * 6 + 0], o1 = rays[r * 6 + 1], o2 = rays[r * 6 + 2];
    const float d0 = rays[r * 6 + 3], d1 = rays[r * 6 + 4], d2 = rays[r * 6 + 5];

    // t_min -- replicate numpy f32 rounding exactly (knife-edge: sample 0 on box face)
    float tm;
    {
        float v0 = (d0 == 0.f) ? 1e-6f : d0;
        float v1 = (d1 == 0.f) ? 1e-6f : d1;
        float v2 = (d2 == 0.f) ? 1e-6f : d2;
        float a0 = __fdiv_rn(__fsub_rn(1.5f, o0), v0), b0 = __fdiv_rn(__fsub_rn(-1.5f, o0), v0);
        float a1 = __fdiv_rn(__fsub_rn(1.5f, o1), v1), b1 = __fdiv_rn(__fsub_rn(-1.5f, o1), v1);
        float a2 = __fdiv_rn(__fsub_rn(1.5f, o2), v2), b2 = __fdiv_rn(__fsub_rn(-1.5f, o2), v2);
        float m0 = fminf(a0, b0), m1 = fminf(a1, b1), m2 = fminf(a2, b2);
        tm = fmaxf(fmaxf(m0, m1), m2);
        tm = fminf(fmaxf(tm, 0.05f), 6.0f);
    }

    // density per-ray coefficients (global reads; unit == lane)
    {
        float qx = Wd1[lane], qy = Wd1[64 + lane], qz = Wd1[128 + lane];
        float qw = bd1[lane], w2 = Wd2[lane];
        float gd = fmaf(d2, qz, fmaf(d1, qy, d0 * qx)) * (2.f / 3.f);
        float kd = fmaf(fmaf(o2, qz, fmaf(o1, qy, o0 * qx)), (2.f / 3.f), qw);
        gkwD[wid][lane] = make_float4(gd, kd, w2, 0.f);
    }

    const float bd2c = bd2[0];
    const float ba2c0 = ba2[0], ba2c1 = ba2[1], ba2c2 = ba2[2];

    __syncthreads();  // apAs/bQ/wscs ready

    // appearance per-ray coefficients (needs folded wac from apAs)
    {
        float4 A = apAs[lane];
        float dc = ba1[lane];
        dc = fmaf(d0, Wa1[27 * 64 + lane], dc);
        dc = fmaf(d1, Wa1[28 * 64 + lane], dc);
        dc = fmaf(d2, Wa1[29 * 64 + lane], dc);
        float ga = fmaf(d2, A.z, fmaf(d1, A.y, d0 * A.x)) * (2.f / 3.f);
        float ka = fmaf(fmaf(o2, A.z, fmaf(o1, A.y, o0 * A.x)), (2.f / 3.f), dc);
        gkA[wid][lane] = make_float2(ga, ka);
    }
    // same-wave LDS produce->consume: ordered by lgkmcnt, no barrier needed

    const float STEPF = (float)(3.0 / 299.001 * 3.0);
    const float zlast2 = __fadd_rn(tm, __fmul_rn(171.f, STEPF));

    float aR0 = 0.f, aR1 = 0.f, aR2 = 0.f;
    float aS0 = 0.f, aS1 = 0.f, aS2 = 0.f;
    float aSw = 0.f;
    float aD = 0.f, aLu = 0.f, aLb = 0.f;
    float Tc = 1.f, Wcar = 0.f, WMc = 0.f;

    // ---- 3 chunks of 64 samples; wave-uniform early exit ----
    for (int c = 0; c < 3; ++c) {
        int i = (c << 6) + lane;
        bool valid = i < NSAMP;
        float z = __fadd_rn(tm, __fmul_rn((float)i, STEPF));
        float x0 = __fadd_rn(o0, __fmul_rn(d0, z));
        float x1 = __fadd_rn(o1, __fmul_rn(d1, z));
        float x2 = __fadd_rn(o2, __fmul_rn(d2, z));
        bool inbox = valid && (x0 >= -1.5f) && (x0 <= 1.5f) && (x1 >= -1.5f) && (x1 <= 1.5f) &&
                     (x2 >= -1.5f) && (x2 <= 1.5f);
        if (__ballot(inbox) == 0ull) break;

        float xn0 = x0 * (2.f / 3.f), xn1 = x1 * (2.f / 3.f), xn2 = x2 * (2.f / 3.f);

        // density MLP: h_u = z*gd_u + kd_u  (1 LDS read + 3 VALU per unit)
        float sp = bd2c;
#pragma unroll 8
        for (int u = 0; u < 64; ++u) {
            float4 g = gkwD[wid][u];
            float h = fmaf(z, g.x, g.y);
            sp = fmaf(fmaxf(h, 0.f), g.z, sp);
        }
        float sigma = inbox ? softplus_f(sp) : 0.f;

        float znext = __fadd_rn(tm, __fmul_rn((float)(i + 1), STEPF));
        float dist = (i < LASTI) ? __fsub_rn(znext, z) : 0.f;
        float alpha = 1.f - __expf(-sigma * dist * 25.f);
        float f = 1.f - alpha + 1e-10f;

        // DPP product scan
        float p = scan_mul64(f);
        float pex = updpp<0x138, 0xf, false>(1.f, p);
        float T = Tc * pex;
        float w = alpha * T;

        float mid = (i < LASTI) ? 0.5f * __fadd_rn(z, znext) : zlast2;
        float wm = w * mid;

        // DPP sum scans
        float sw = scan_add64(w);
        float swm = scan_add64(wm);
        float wex = updpp<0x138, 0xf, true>(0.f, sw);
        float wmex = updpp<0x138, 0xf, true>(0.f, swm);

        aLb += wm * (Wcar + wex) - w * (WMc + wmex);
        aLu = fmaf(dist * w, w, aLu);
        aD = fmaf(w, z, aD);

        Tc *= RL(p, 63);
        Wcar += RL(sw, 63);
        WMc += RL(swm, 63);

        // appearance (only where w > W_THRES): h_u = z*ga_u + ka_u
        float wapp = (w > 1e-4f) ? w : 0.f;
        if (__ballot(wapp > 0.f) != 0ull) {
            float c0 = 0.f, c1 = 0.f, c2 = 0.f;
#pragma unroll 8
            for (int u = 0; u < 64; ++u) {
                float2 g = gkA[wid][u];
                float4 b = bQ[u];
                float h = fmaf(z, g.x, g.y);
                h = fmaxf(h, 0.f);
                c0 = fmaf(h, b.x, c0);
                c1 = fmaf(h, b.y, c1);
                c2 = fmaf(h, b.z, c2);
            }
            aR0 = fmaf(wapp, sigmoid_f(c0 + ba2c0), aR0);
            aR1 = fmaf(wapp, sigmoid_f(c1 + ba2c1), aR1);
            aR2 = fmaf(wapp, sigmoid_f(c2 + ba2c2), aR2);
            aS0 = fmaf(wapp, xn0, aS0);
            aS1 = fmaf(wapp, xn1, aS1);
            aS2 = fmaf(wapp, xn2, aS2);
            aSw += wapp;
        }

        if (Tc < 1e-8f) break;  // all later weights < 1e-8 << W_THRES
    }

    // wave reductions
    aR0 = wave_sum64(aR0); aR1 = wave_sum64(aR1); aR2 = wave_sum64(aR2);
    aS0 = wave_sum64(aS0); aS1 = wave_sum64(aS1); aS2 = wave_sum64(aS2);
    aSw = wave_sum64(aSw);
    aD = wave_sum64(aD);
    aLu = wave_sum64(aLu);
    aLb = wave_sum64(aLb);

    float opac = Wcar;
    int wb = *whitebg_p;
    float bg = wb ? (1.f - opac) : 0.f;

    float* out_rgb = out;
    float* out_sem = out + 24576;
    float* out_inst = out + 188416;
    float* out_dep = out + 319488;

    if (lane < 3) {
        float rv = (lane == 0 ? aR0 : (lane == 1 ? aR1 : aR2)) + bg;
        rv = fminf(fmaxf(rv, 0.f), 1.f);
        out_rgb[r * 3 + lane] = rv;
    }
    if (lane < 20) {
        float sv = aS0 * wscs[lane] + aS1 * wscs[20 + lane] + aS2 * wscs[40 + lane] +
                   aSw * bsmS[lane];
        out_sem[r * 20 + lane] = sv;
    }
    if (lane < 16) {
        float iv = aS0 * Wi[lane] + aS1 * Wi[16 + lane] + aS2 * Wi[32 + lane];
        out_inst[r * 16 + lane] = iv;
    }
    if (lane == 0) {
        out_dep[r] = aD;
        wsdist[r] = aLu * (1.f / 3.f) + 2.f * aLb;
    }
}

__global__ void reduce_dist_kernel(const float* __restrict__ ws, float* __restrict__ out) {
    __shared__ float sm[256];
    int t = threadIdx.x;
    float a = 0.f;
    const float4* w4 = (const float4*)ws;
    for (int i = t; i < NRAYS / 4; i += 256) {
        float4 v = w4[i];
        a += (v.x + v.y) + (v.z + v.w);
    }
    sm[t] = a;
    __syncthreads();
    for (int st = 128; st > 0; st >>= 1) {
        if (t < st) sm[t] += sm[t + st];
        __syncthreads();
    }
    if (t == 0) out[0] = sm[0] * (1.f / (float)NRAYS);
}

extern "C" void kernel_launch(void* const* d_in, const int* in_sizes, int n_in,
                              void* d_out, int out_size, void* d_ws, size_t ws_size,
                              hipStream_t stream) {
    const float* rays = (const float*)d_in[0];
    const float* Wd1  = (const float*)d_in[1];
    const float* bd1  = (const float*)d_in[2];
    const float* Wd2  = (const float*)d_in[3];
    const float* bd2  = (const float*)d_in[4];
    const float* Wapp = (const float*)d_in[5];
    const float* Wa1  = (const float*)d_in[6];
    const float* ba1  = (const float*)d_in[7];
    const float* Wa2  = (const float*)d_in[8];
    const float* ba2  = (const float*)d_in[9];
    const float* Wsf  = (const float*)d_in[10];
    const float* Wsm  = (const float*)d_in[11];
    const float* bsm  = (const float*)d_in[12];
    const float* Wi   = (const float*)d_in[13];
    const int* wb     = (const int*)d_in[15];

    float* out = (float*)d_out;
    float* wsd = (float*)d_ws;   // 8192 f32 per-ray dist values

    render_kernel<<<NBLK, 256, 0, stream>>>(rays, Wd1, bd1, Wd2, bd2, Wapp, Wa1, ba1,
                                            Wa2, ba2, Wsf, Wsm, bsm, Wi, wb, out, wsd);
    reduce_dist_kernel<<<1, 256, 0, stream>>>(wsd, out + 327680);
}

// Round 15
// 30.648 us; speedup vs baseline: 1.0601x; 1.0601x over previous
//
#include <hip/hip_runtime.h>

#define NRAYS 8192
#define NSAMP 173
#define LASTI 172
#define NBLK  (NRAYS / 4)

__device__ __forceinline__ float RL(float x, int u) {
    return __int_as_float(__builtin_amdgcn_readlane(__float_as_int(x), u));
}

// DPP helper: result = (lane enabled by masks && src in range) ? src[dpp] : old
template <int CTRL, int RM, bool BC>
__device__ __forceinline__ float updpp(float old, float x) {
    return __int_as_float(__builtin_amdgcn_update_dpp(
        __float_as_int(old), __float_as_int(x), CTRL, RM, 0xf, BC));
}

// wave64 inclusive add-scan
__device__ __forceinline__ float scan_add64(float x) {
    x += updpp<0x111, 0xf, true>(0.f, x);
    x += updpp<0x112, 0xf, true>(0.f, x);
    x += updpp<0x114, 0xf, true>(0.f, x);
    x += updpp<0x118, 0xf, true>(0.f, x);
    x += updpp<0x142, 0xa, true>(0.f, x);
    x += updpp<0x143, 0xc, true>(0.f, x);
    return x;
}

// wave64 inclusive mul-scan
__device__ __forceinline__ float scan_mul64(float x) {
    x *= updpp<0x111, 0xf, false>(1.f, x);
    x *= updpp<0x112, 0xf, false>(1.f, x);
    x *= updpp<0x114, 0xf, false>(1.f, x);
    x *= updpp<0x118, 0xf, false>(1.f, x);
    x *= updpp<0x142, 0xa, false>(1.f, x);
    x *= updpp<0x143, 0xc, false>(1.f, x);
    return x;
}

__device__ __forceinline__ float wave_sum64(float v) {
    return RL(scan_add64(v), 63);
}

__device__ __forceinline__ float softplus_f(float x) {
    if (x > 15.f) return x;
    return __logf(1.f + __expf(x));
}
__device__ __forceinline__ float sigmoid_f(float x) {
    return 1.f / (1.f + __expf(-x));
}

__launch_bounds__(256, 8)
__global__ void render_kernel(
    const float* __restrict__ rays,
    const float* __restrict__ Wd1, const float* __restrict__ bd1,
    const float* __restrict__ Wd2, const float* __restrict__ bd2,
    const float* __restrict__ Wapp, const float* __restrict__ Wa1,
    const float* __restrict__ ba1, const float* __restrict__ Wa2,
    const float* __restrict__ ba2, const float* __restrict__ Wsf,
    const float* __restrict__ Wsm, const float* __restrict__ bsm,
    const float* __restrict__ Wi,
    const int* __restrict__ whitebg_p,
    float* __restrict__ out,
    float* __restrict__ wsdist)
{
    // per-block folded weight tables in LDS (broadcast reads, no conflicts)
    __shared__ float4 qd4[64];   // Wd1 cols + bd1
    __shared__ float  wd2s[64];  // Wd2
    __shared__ float4 apAs[64];  // (wac0, wac1, wac2, Wa2[u][0]);  wac = Wapp @ Wa1[:27]
    __shared__ float2 apBs[64];  // (Wa2[u][1], Wa2[u][2])
    __shared__ float  wscs[60];  // (Wsf @ Wsm)[m*20+s]
    __shared__ float  bsmS[20];

    const int t = threadIdx.x;
    const int wid = t >> 6, lane = t & 63;
    const int r = blockIdx.x * 4 + wid;

    // ---- preamble: fold tables (L2-hot after first blocks) ----
    if (t < 64) {
        qd4[t] = make_float4(Wd1[t], Wd1[64 + t], Wd1[128 + t], bd1[t]);
        wd2s[t] = Wd2[t];
    } else if (t < 128) {
        int u = t - 64;
        apBs[u] = make_float2(Wa2[3 * u + 1], Wa2[3 * u + 2]);
    } else if (t < 192) {
        int u = t - 128;
        float s0 = 0.f, s1 = 0.f, s2 = 0.f;
        for (int j = 0; j < 27; ++j) {
            float w = Wa1[j * 64 + u];
            s0 = fmaf(Wapp[j], w, s0);
            s1 = fmaf(Wapp[27 + j], w, s1);
            s2 = fmaf(Wapp[54 + j], w, s2);
        }
        apAs[u] = make_float4(s0, s1, s2, Wa2[3 * u]);
    } else {
        for (int job = t - 192; job < 80; job += 64) {
            if (job < 60) {
                int m = job / 20, s = job % 20;
                float a = 0.f;
                for (int k = 0; k < 32; ++k) a = fmaf(Wsf[m * 32 + k], Wsm[k * 20 + s], a);
                wscs[job] = a;
            } else {
                bsmS[job - 60] = bsm[job - 60];
            }
        }
    }

    // ray (wave-uniform)
    const float o0 = rays[r * 6 + 0], o1 = rays[r * 6 + 1], o2 = rays[r * 6 + 2];
    const float d0 = rays[r * 6 + 3], d1 = rays[r * 6 + 4], d2 = rays[r * 6 + 5];

    // t_min -- replicate numpy f32 rounding exactly (knife-edge: sample 0 on box face)
    float tm;
    {
        float v0 = (d0 == 0.f) ? 1e-6f : d0;
        float v1 = (d1 == 0.f) ? 1e-6f : d1;
        float v2 = (d2 == 0.f) ? 1e-6f : d2;
        float a0 = __fdiv_rn(__fsub_rn(1.5f, o0), v0), b0 = __fdiv_rn(__fsub_rn(-1.5f, o0), v0);
        float a1 = __fdiv_rn(__fsub_rn(1.5f, o1), v1), b1 = __fdiv_rn(__fsub_rn(-1.5f, o1), v1);
        float a2 = __fdiv_rn(__fsub_rn(1.5f, o2), v2), b2 = __fdiv_rn(__fsub_rn(-1.5f, o2), v2);
        float m0 = fminf(a0, b0), m1 = fminf(a1, b1), m2 = fminf(a2, b2);
        tm = fmaxf(fmaxf(m0, m1), m2);
        tm = fminf(fmaxf(tm, 0.05f), 6.0f);
    }

    // per-ray appearance dconst for unit==lane (lane-distributed; broadcast via readlane)
    float dcr;
    {
        float b = ba1[lane];
        b = fmaf(d0, Wa1[27 * 64 + lane], b);
        b = fmaf(d1, Wa1[28 * 64 + lane], b);
        b = fmaf(d2, Wa1[29 * 64 + lane], b);
        dcr = b;
    }

    const float bd2c = bd2[0];
    const float ba2c0 = ba2[0], ba2c1 = ba2[1], ba2c2 = ba2[2];

    __syncthreads();

    const float STEPF = (float)(3.0 / 299.001 * 3.0);
    const float zlast2 = __fadd_rn(tm, __fmul_rn(171.f, STEPF));

    float aR0 = 0.f, aR1 = 0.f, aR2 = 0.f;
    float aS0 = 0.f, aS1 = 0.f, aS2 = 0.f;
    float aSw = 0.f;
    float aD = 0.f, aLu = 0.f, aLb = 0.f;
    float Tc = 1.f, Wcar = 0.f, WMc = 0.f;

    // ---- 3 chunks of 64 samples; wave-uniform early exit (T collapses ~sample 30) ----
    for (int c = 0; c < 3; ++c) {
        int i = (c << 6) + lane;
        bool valid = i < NSAMP;
        float z = __fadd_rn(tm, __fmul_rn((float)i, STEPF));
        float x0 = __fadd_rn(o0, __fmul_rn(d0, z));
        float x1 = __fadd_rn(o1, __fmul_rn(d1, z));
        float x2 = __fadd_rn(o2, __fmul_rn(d2, z));
        bool inbox = valid && (x0 >= -1.5f) && (x0 <= 1.5f) && (x1 >= -1.5f) && (x1 <= 1.5f) &&
                     (x2 >= -1.5f) && (x2 <= 1.5f);
        if (__ballot(inbox) == 0ull) break;  // in-box span is contiguous from sample 0

        float xn0 = x0 * (2.f / 3.f), xn1 = x1 * (2.f / 3.f), xn2 = x2 * (2.f / 3.f);

        // density MLP (LDS broadcast weights)
        float sp = bd2c;
#pragma unroll 8
        for (int u = 0; u < 64; ++u) {
            float4 q = qd4[u];
            float h = fmaf(xn0, q.x, fmaf(xn1, q.y, fmaf(xn2, q.z, q.w)));
            sp = fmaf(fmaxf(h, 0.f), wd2s[u], sp);
        }
        float sigma = inbox ? softplus_f(sp) : 0.f;

        float znext = __fadd_rn(tm, __fmul_rn((float)(i + 1), STEPF));
        float dist = (i < LASTI) ? __fsub_rn(znext, z) : 0.f;
        float alpha = 1.f - __expf(-sigma * dist * 25.f);
        float f = 1.f - alpha + 1e-10f;

        // DPP product scan
        float p = scan_mul64(f);
        float pex = updpp<0x138, 0xf, false>(1.f, p);  // wave_shr1, lane0 -> 1
        float T = Tc * pex;
        float w = alpha * T;

        float mid = (i < LASTI) ? 0.5f * __fadd_rn(z, znext) : zlast2;
        float wm = w * mid;

        // DPP sum scans
        float sw = scan_add64(w);
        float swm = scan_add64(wm);
        float wex = updpp<0x138, 0xf, true>(0.f, sw);
        float wmex = updpp<0x138, 0xf, true>(0.f, swm);

        aLb += wm * (Wcar + wex) - w * (WMc + wmex);
        aLu = fmaf(dist * w, w, aLu);
        aD = fmaf(w, z, aD);

        Tc *= RL(p, 63);
        Wcar += RL(sw, 63);
        WMc += RL(swm, 63);

        // appearance (only where w > W_THRES)
        float wapp = (w > 1e-4f) ? w : 0.f;
        if (__ballot(wapp > 0.f) != 0ull) {
            float c0 = 0.f, c1 = 0.f, c2 = 0.f;
#pragma unroll 8
            for (int u = 0; u < 64; ++u) {
                float4 A4 = apAs[u];
                float2 B2 = apBs[u];
                float dcu = RL(dcr, u);
                float h = fmaf(xn0, A4.x, fmaf(xn1, A4.y, fmaf(xn2, A4.z, dcu)));
                h = fmaxf(h, 0.f);
                c0 = fmaf(h, A4.w, c0);
                c1 = fmaf(h, B2.x, c1);
                c2 = fmaf(h, B2.y, c2);
            }
            aR0 = fmaf(wapp, sigmoid_f(c0 + ba2c0), aR0);
            aR1 = fmaf(wapp, sigmoid_f(c1 + ba2c1), aR1);
            aR2 = fmaf(wapp, sigmoid_f(c2 + ba2c2), aR2);
            aS0 = fmaf(wapp, xn0, aS0);
            aS1 = fmaf(wapp, xn1, aS1);
            aS2 = fmaf(wapp, xn2, aS2);
            aSw += wapp;
        }

        if (Tc < 1e-8f) break;  // all later weights < 1e-8 << W_THRES
    }

    // wave reductions (DPP scan + readlane)
    aR0 = wave_sum64(aR0); aR1 = wave_sum64(aR1); aR2 = wave_sum64(aR2);
    aS0 = wave_sum64(aS0); aS1 = wave_sum64(aS1); aS2 = wave_sum64(aS2);
    aSw = wave_sum64(aSw);
    aD = wave_sum64(aD);
    aLu = wave_sum64(aLu);
    aLb = wave_sum64(aLb);

    float opac = Wcar;
    int wb = *whitebg_p;
    float bg = wb ? (1.f - opac) : 0.f;

    float* out_rgb = out;
    float* out_sem = out + 24576;
    float* out_inst = out + 188416;
    float* out_dep = out + 319488;

    if (lane < 3) {
        float rv = (lane == 0 ? aR0 : (lane == 1 ? aR1 : aR2)) + bg;
        rv = fminf(fmaxf(rv, 0.f), 1.f);
        out_rgb[r * 3 + lane] = rv;
    }
    if (lane < 20) {
        float sv = aS0 * wscs[lane] + aS1 * wscs[20 + lane] + aS2 * wscs[40 + lane] +
                   aSw * bsmS[lane];
        out_sem[r * 20 + lane] = sv;
    }
    if (lane < 16) {
        float iv = aS0 * Wi[lane] + aS1 * Wi[16 + lane] + aS2 * Wi[32 + lane];
        out_inst[r * 16 + lane] = iv;
    }
    if (lane == 0) {
        out_dep[r] = aD;
        wsdist[r] = aLu * (1.f / 3.f) + 2.f * aLb;
    }
}

__global__ void reduce_dist_kernel(const float* __restrict__ ws, float* __restrict__ out) {
    __shared__ float sm[256];
    int t = threadIdx.x;
    float a = 0.f;
    const float4* w4 = (const float4*)ws;
    for (int i = t; i < NRAYS / 4; i += 256) {
        float4 v = w4[i];
        a += (v.x + v.y) + (v.z + v.w);
    }
    sm[t] = a;
    __syncthreads();
    for (int st = 128; st > 0; st >>= 1) {
        if (t < st) sm[t] += sm[t + st];
        __syncthreads();
    }
    if (t == 0) out[0] = sm[0] * (1.f / (float)NRAYS);
}

extern "C" void kernel_launch(void* const* d_in, const int* in_sizes, int n_in,
                              void* d_out, int out_size, void* d_ws, size_t ws_size,
                              hipStream_t stream) {
    const float* rays = (const float*)d_in[0];
    const float* Wd1  = (const float*)d_in[1];
    const float* bd1  = (const float*)d_in[2];
    const float* Wd2  = (const float*)d_in[3];
    const float* bd2  = (const float*)d_in[4];
    const float* Wapp = (const float*)d_in[5];
    const float* Wa1  = (const float*)d_in[6];
    const float* ba1  = (const float*)d_in[7];
    const float* Wa2  = (const float*)d_in[8];
    const float* ba2  = (const float*)d_in[9];
    const float* Wsf  = (const float*)d_in[10];
    const float* Wsm  = (const float*)d_in[11];
    const float* bsm  = (const float*)d_in[12];
    const float* Wi   = (const float*)d_in[13];
    const int* wb     = (const int*)d_in[15];

    float* out = (float*)d_out;
    float* wsd = (float*)d_ws;   // 8192 f32 per-ray dist values

    render_kernel<<<NBLK, 256, 0, stream>>>(rays, Wd1, bd1, Wd2, bd2, Wapp, Wa1, ba1,
                                            Wa2, ba2, Wsf, Wsm, bsm, Wi, wb, out, wsd);
    reduce_dist_kernel<<<1, 256, 0, stream>>>(wsd, out + 327680);
}